// Round 8
// baseline (434.288 us; speedup 1.0000x reference)
//
#include <hip/hip_runtime.h>
#include <hip/hip_fp16.h>

// GraphEmbedding2: 3-layer GCN (DGL GraphConv, norm='both') + per-graph mean pooling.
// N=50000 nodes, E=600000 edges, d=128, G=64 graphs.
// fp16 gather operands (R6); agg+gemm fused per layer (R7): gather -> LDS -> GEMM.

#define DIM 128

// ---------------------------------------------------------------- degree histogram (LDS)
#define HIST_R 4
#define HIST_S 32
#define NPR 12500          // nodes per range
#define LDSW (NPR / 2)     // 6250 u32 words, 25 KB LDS

__global__ __launch_bounds__(256) void k_hist(const int* __restrict__ src,
                                              const int* __restrict__ dst,
                                              unsigned* __restrict__ partial, int E) {
    __shared__ unsigned hist[LDSW];
    int b = blockIdx.x;
    int a = b / (HIST_R * HIST_S);       // 0: src, 1: dst
    int r = (b / HIST_S) % HIST_R;       // node range
    int s = b % HIST_S;                  // edge slice
    const int* arr = a ? dst : src;
    for (int i = threadIdx.x; i < LDSW; i += 256) hist[i] = 0;
    __syncthreads();
    int chunk = (E + HIST_S - 1) / HIST_S;
    int e0 = s * chunk;
    int e1 = min(e0 + chunk, E);
    unsigned base = (unsigned)(r * NPR);
    for (int i = e0 + threadIdx.x; i < e1; i += 256) {
        unsigned n = (unsigned)arr[i] - base;
        if (n < NPR) atomicAdd(&hist[n >> 1], 1u << ((n & 1) * 16));
    }
    __syncthreads();
    unsigned* outp = partial + ((size_t)(a * HIST_R + r) * HIST_S + s) * LDSW;
    for (int i = threadIdx.x; i < LDSW; i += 256) outp[i] = hist[i];
}

__global__ void k_hist_merge(const unsigned* __restrict__ partial,
                             float* __restrict__ ns, float* __restrict__ nd,
                             int* __restrict__ inc, int N) {
    int t = blockIdx.x * blockDim.x + threadIdx.x;
    const int total_w = HIST_R * LDSW;   // words per array
    if (t >= 2 * total_w) return;
    int a = t / total_w;
    int wg = t % total_w;
    int r = wg / LDSW;
    int w = wg % LDSW;
    const unsigned* p = partial + ((size_t)(a * HIST_R + r) * HIST_S) * LDSW + w;
    unsigned sum = 0;
#pragma unroll
    for (int s = 0; s < HIST_S; ++s) sum += p[(size_t)s * LDSW];
    int n0 = r * NPR + w * 2;
    int d0 = (int)(sum & 0xFFFFu);
    int d1 = (int)(sum >> 16);
    if (a == 0) {
        if (n0 < N)     ns[n0]     = rsqrtf(fmaxf((float)d0, 1.0f));
        if (n0 + 1 < N) ns[n0 + 1] = rsqrtf(fmaxf((float)d1, 1.0f));
    } else {
        if (n0 < N)     { nd[n0]     = rsqrtf(fmaxf((float)d0, 1.0f)); inc[n0]     = d0; }
        if (n0 + 1 < N) { nd[n0 + 1] = rsqrtf(fmaxf((float)d1, 1.0f)); inc[n0 + 1] = d1; }
    }
}

// ---------------------------------------------------------------- CSR build
__global__ void k_scan_partial(const int* __restrict__ inc, int* __restrict__ bsum, int N) {
    __shared__ int s[256];
    int i = blockIdx.x * 256 + threadIdx.x;
    int t = threadIdx.x;
    s[t] = (i < N) ? inc[i] : 0;
    __syncthreads();
    for (int off = 128; off > 0; off >>= 1) {
        if (t < off) s[t] += s[t + off];
        __syncthreads();
    }
    if (t == 0) bsum[blockIdx.x] = s[0];
}

__global__ void k_scan_top(int* __restrict__ bsum, int nb) {
    __shared__ int s[256];
    int t = threadIdx.x;
    int v = (t < nb) ? bsum[t] : 0;
    s[t] = v;
    __syncthreads();
    for (int off = 1; off < 256; off <<= 1) {
        int u = (t >= off) ? s[t - off] : 0;
        __syncthreads();
        s[t] += u;
        __syncthreads();
    }
    if (t < nb) bsum[t] = s[t] - v;  // exclusive
}

__global__ void k_scan_write(const int* __restrict__ inc, const int* __restrict__ bsum,
                             int* __restrict__ row_ptr, int* __restrict__ cursor, int N) {
    __shared__ int s[256];
    int i = blockIdx.x * 256 + threadIdx.x;
    int t = threadIdx.x;
    int v = (i < N) ? inc[i] : 0;
    s[t] = v;
    __syncthreads();
    for (int off = 1; off < 256; off <<= 1) {
        int u = (t >= off) ? s[t - off] : 0;
        __syncthreads();
        s[t] += u;
        __syncthreads();
    }
    int ex = bsum[blockIdx.x] + s[t] - v;  // global exclusive prefix
    if (i < N) { row_ptr[i] = ex; cursor[i] = ex; }
    if (i == N - 1) row_ptr[N] = ex + v;
}

__global__ void k_fill(const int* __restrict__ src, const int* __restrict__ dst,
                       int* __restrict__ cursor, int* __restrict__ csr, int E) {
    int e = blockIdx.x * blockDim.x + threadIdx.x;
    if (e < E) {
        int p = atomicAdd(&cursor[dst[e]], 1);
        csr[p] = src[e];
    }
}

// ---------------------------------------------------------------- h -> fp16(h * ns)
__global__ void k_h2half(const float4* __restrict__ h, const float* __restrict__ ns,
                         uint2* __restrict__ A, int N) {
    int i = blockIdx.x * blockDim.x + threadIdx.x;  // N*32 float4s
    if (i < N * 32) {
        int n = i >> 5;
        float s = ns[n];
        float4 v = h[i];
        __half2 p0 = __floats2half2_rn(v.x * s, v.y * s);
        __half2 p1 = __floats2half2_rn(v.z * s, v.w * s);
        uint2 o;
        o.x = *(unsigned*)&p0;
        o.y = *(unsigned*)&p1;
        A[i] = o;
    }
}

// ---------------------------------------------------------------- fused layer
// Phase 1: each of 4 waves gather-aggregates 8 nodes (paired-edge fp16 gather,
// x4 unroll, fp32 accumulate, *nd) straight into LDS xsT[k][row].
// Phase 2: 32x128 GEMM from LDS (4x4 register tile/thread) + bias + relu;
// HALF_OUT: write fp16(x * ns) (next layer's gather operand), else fp32.
template <bool HALF_OUT>
__global__ __launch_bounds__(256) void k_layer(
    const uint2* __restrict__ Ain, const int* __restrict__ row_ptr,
    const int* __restrict__ csr, const float* __restrict__ nd,
    const float* __restrict__ W, const float* __restrict__ bias,
    const float* __restrict__ ns, void* __restrict__ Xout, int N) {
    __shared__ float xsT[DIM][36];  // [k][row], +pad
    __shared__ float ws[32][128];   // W k-chunk

    int tid = threadIdx.x;
    int wave = tid >> 6;     // 0..3
    int lane = tid & 63;
    int half = lane >> 5;    // paired-edge half
    int l8 = lane & 31;      // 8-byte slot within 256B fp16 row
    int r0 = blockIdx.x * 32;

    // ---- phase 1: gather-aggregate
    for (int i = 0; i < 8; ++i) {
        int row = wave * 8 + i;
        int node = r0 + row;
        float ax = 0.f, ay = 0.f, az = 0.f, aw = 0.f;
        if (node < N) {
            int e0 = row_ptr[node];
            int e1 = row_ptr[node + 1];
            auto acc4 = [&](uint2 u) {
                __half2 p0 = *(__half2*)&u.x;
                __half2 p1 = *(__half2*)&u.y;
                float2 f0 = __half22float2(p0);
                float2 f1 = __half22float2(p1);
                ax += f0.x; ay += f0.y; az += f1.x; aw += f1.y;
            };
            int e = e0;
            for (; e + 8 <= e1; e += 8) {
                int s0 = csr[e + half];
                int s1 = csr[e + 2 + half];
                int s2 = csr[e + 4 + half];
                int s3 = csr[e + 6 + half];
                uint2 u0 = Ain[(size_t)s0 * 32 + l8];
                uint2 u1 = Ain[(size_t)s1 * 32 + l8];
                uint2 u2 = Ain[(size_t)s2 * 32 + l8];
                uint2 u3 = Ain[(size_t)s3 * 32 + l8];
                acc4(u0); acc4(u1); acc4(u2); acc4(u3);
            }
            for (; e + 2 <= e1; e += 2) {
                int s0 = csr[e + half];
                acc4(Ain[(size_t)s0 * 32 + l8]);
            }
            if (e < e1 && half == 0) {
                int s0 = csr[e];
                acc4(Ain[(size_t)s0 * 32 + l8]);
            }
        }
        ax += __shfl_xor(ax, 32);
        ay += __shfl_xor(ay, 32);
        az += __shfl_xor(az, 32);
        aw += __shfl_xor(aw, 32);
        if (half == 0 && node < N) {
            float sc = nd[node];
            xsT[4 * l8 + 0][row] = ax * sc;
            xsT[4 * l8 + 1][row] = ay * sc;
            xsT[4 * l8 + 2][row] = az * sc;
            xsT[4 * l8 + 3][row] = aw * sc;
        }
    }
    __syncthreads();

    // ---- phase 2: GEMM from LDS
    int tx = tid & 31;      // col group
    int ty = tid >> 5;      // row group
    float acc[4][4] = {};

    for (int k0 = 0; k0 < 128; k0 += 32) {
#pragma unroll
        for (int j = 0; j < 4; ++j) {
            int idx = tid + j * 256;
            int row = idx >> 5;
            int cq = idx & 31;
            *(float4*)&ws[row][cq * 4] =
                *(const float4*)&W[(size_t)(k0 + row) * DIM + cq * 4];
        }
        __syncthreads();
#pragma unroll
        for (int kk = 0; kk < 32; ++kk) {
            float4 a = *(const float4*)&xsT[k0 + kk][ty * 4];
            float4 w = *(const float4*)&ws[kk][tx * 4];
            acc[0][0] += a.x * w.x; acc[0][1] += a.x * w.y; acc[0][2] += a.x * w.z; acc[0][3] += a.x * w.w;
            acc[1][0] += a.y * w.x; acc[1][1] += a.y * w.y; acc[1][2] += a.y * w.z; acc[1][3] += a.y * w.w;
            acc[2][0] += a.z * w.x; acc[2][1] += a.z * w.y; acc[2][2] += a.z * w.z; acc[2][3] += a.z * w.w;
            acc[3][0] += a.w * w.x; acc[3][1] += a.w * w.y; acc[3][2] += a.w * w.z; acc[3][3] += a.w * w.w;
        }
        __syncthreads();
    }

    float4 bb = *(const float4*)&bias[tx * 4];
#pragma unroll
    for (int i = 0; i < 4; ++i) {
        int row = r0 + ty * 4 + i;
        if (row >= N) continue;
        float o0 = fmaxf(acc[i][0] + bb.x, 0.0f);
        float o1 = fmaxf(acc[i][1] + bb.y, 0.0f);
        float o2 = fmaxf(acc[i][2] + bb.z, 0.0f);
        float o3 = fmaxf(acc[i][3] + bb.w, 0.0f);
        if (HALF_OUT) {
            float s = ns[row];
            __half2 p0 = __floats2half2_rn(o0 * s, o1 * s);
            __half2 p1 = __floats2half2_rn(o2 * s, o3 * s);
            uint2 o;
            o.x = *(unsigned*)&p0;
            o.y = *(unsigned*)&p1;
            ((uint2*)Xout)[(size_t)row * 32 + tx] = o;
        } else {
            float4 o = make_float4(o0, o1, o2, o3);
            ((float4*)Xout)[(size_t)row * 32 + tx] = o;
        }
    }
}

// ---------------------------------------------------------------- pooling
#define POOL_NODES 32
__global__ void k_pool_partial(const float* __restrict__ X, const int* __restrict__ gid,
                               float* __restrict__ gsum, int* __restrict__ gcnt, int N) {
    int n0 = blockIdx.x * POOL_NODES;
    int d = threadIdx.x;  // 0..127
    int nend = min(n0 + POOL_NODES, N);
    float run = 0.0f;
    int cnt = 0;
    int curg = -1;
    for (int n = n0; n < nend; ++n) {
        int g = gid[n];
        if (g != curg) {
            if (cnt > 0) {
                atomicAdd(&gsum[curg * DIM + d], run);
                if (d == 0) atomicAdd(&gcnt[curg], cnt);
            }
            run = 0.0f; cnt = 0; curg = g;
        }
        run += X[(size_t)n * DIM + d];
        cnt++;
    }
    if (cnt > 0) {
        atomicAdd(&gsum[curg * DIM + d], run);
        if (d == 0) atomicAdd(&gcnt[curg], cnt);
    }
}

__global__ void k_finalize(const float* __restrict__ gsum, const int* __restrict__ gcnt,
                           float* __restrict__ out, int G) {
    int i = blockIdx.x * blockDim.x + threadIdx.x;
    if (i < G * DIM) {
        int g = i >> 7;
        float c = fmaxf((float)gcnt[g], 1.0f);
        out[i] = gsum[i] / c;
    }
}

// ---------------------------------------------------------------- launch
extern "C" void kernel_launch(void* const* d_in, const int* in_sizes, int n_in,
                              void* d_out, int out_size, void* d_ws, size_t ws_size,
                              hipStream_t stream) {
    const float* h   = (const float*)d_in[0];
    const int*   src = (const int*)d_in[1];
    const int*   dst = (const int*)d_in[2];
    const int*   gid = (const int*)d_in[3];
    const float* W1  = (const float*)d_in[4];
    const float* b1  = (const float*)d_in[5];
    const float* W2  = (const float*)d_in[6];
    const float* b2  = (const float*)d_in[7];
    const float* W3  = (const float*)d_in[8];
    const float* b3  = (const float*)d_in[9];

    const int N = in_sizes[0] / DIM;   // 50000
    const int E = in_sizes[1];         // 600000
    const int G = 64;
    float* out = (float*)d_out;

    char* ws = (char*)d_ws;
    size_t off = 0;
    auto alloc = [&](size_t bytes) -> void* {
        void* p = ws + off;
        off += (bytes + 255) & ~(size_t)255;
        return p;
    };
    const int scanBlocks = (N + 255) / 256;
    uint2* Ah0     = (uint2*)alloc((size_t)N * DIM * 2);  // fp16 ping
    uint2* Ah1     = (uint2*)alloc((size_t)N * DIM * 2);  // fp16 pong
    float* X3      = (float*)alloc((size_t)N * DIM * 4);  // layer-3 fp32 output
    float* ns      = (float*)alloc((size_t)N * 4);
    float* nd      = (float*)alloc((size_t)N * 4);
    int*   inc     = (int*)alloc((size_t)N * 4);
    unsigned* partial = (unsigned*)alloc((size_t)2 * HIST_R * HIST_S * LDSW * 4);
    int*   row_ptr = (int*)alloc((size_t)(N + 1) * 4);
    int*   cursor  = (int*)alloc((size_t)N * 4);
    int*   csr     = (int*)alloc((size_t)E * 4);
    float* gsum    = (float*)alloc((size_t)G * DIM * 4);
    int*   gcnt    = (int*)alloc((size_t)G * 4);
    int*   bsum    = (int*)alloc((size_t)scanBlocks * 4);

    hipMemsetAsync(gsum, 0, (size_t)G * DIM * 4, stream);
    hipMemsetAsync(gcnt, 0, (size_t)G * 4, stream);

    // degrees via LDS histograms (no global atomics)
    k_hist<<<2 * HIST_R * HIST_S, 256, 0, stream>>>(src, dst, partial, E);
    int mergeThreads = 2 * HIST_R * LDSW;
    k_hist_merge<<<(mergeThreads + 255) / 256, 256, 0, stream>>>(partial, ns, nd, inc, N);

    k_scan_partial<<<scanBlocks, 256, 0, stream>>>(inc, bsum, N);
    k_scan_top<<<1, 256, 0, stream>>>(bsum, scanBlocks);
    k_scan_write<<<scanBlocks, 256, 0, stream>>>(inc, bsum, row_ptr, cursor, N);
    k_fill<<<(E + 255) / 256, 256, 0, stream>>>(src, dst, cursor, csr, E);

    int layerBlocks = (N + 31) / 32;

    // Ah0 = fp16(h * ns); fused layers ping-pong (gather reads whole buffer ->
    // cannot write in place)
    k_h2half<<<(N * 32 + 255) / 256, 256, 0, stream>>>((const float4*)h, ns, Ah0, N);
    k_layer<true><<<layerBlocks, 256, 0, stream>>>(Ah0, row_ptr, csr, nd, W1, b1, ns, Ah1, N);
    k_layer<true><<<layerBlocks, 256, 0, stream>>>(Ah1, row_ptr, csr, nd, W2, b2, ns, Ah0, N);
    k_layer<false><<<layerBlocks, 256, 0, stream>>>(Ah0, row_ptr, csr, nd, W3, b3, ns, X3, N);

    k_pool_partial<<<(N + POOL_NODES - 1) / POOL_NODES, 128, 0, stream>>>(X3, gid, gsum, gcnt, N);
    k_finalize<<<(G * DIM + 255) / 256, 256, 0, stream>>>(gsum, gcnt, out, G);
}

// Round 9
// 336.042 us; speedup vs baseline: 1.2924x; 1.2924x over previous
//
#include <hip/hip_runtime.h>
#include <hip/hip_fp16.h>

// GraphEmbedding2: 3-layer GCN (DGL GraphConv, norm='both') + per-graph mean pooling.
// N=50000 nodes, E=600000 edges, d=128, G=64 graphs.
// fp16 gather operands (R6). R7 fusion REVERTED (91µs vs 46µs: occupancy 23% +
// 3M LDS bank conflicts — latency-bound gather must keep its own high-TLP kernel).
// R8: CSR fill via per-slice LDS cursors derived from the degree histograms
// (zero global atomics anywhere in the pipeline).

#define DIM 128

// ---------------------------------------------------------------- degree histogram (LDS)
#define HIST_R 4
#define HIST_S 64
#define NPR 12500          // nodes per range (HIST_R * NPR = 50000)
#define LDSW (NPR / 2)     // 6250 u32 words, 25 KB LDS

__global__ __launch_bounds__(256) void k_hist(const int* __restrict__ src,
                                              const int* __restrict__ dst,
                                              unsigned* __restrict__ partial, int E) {
    __shared__ unsigned hist[LDSW];
    int b = blockIdx.x;
    int a = b / (HIST_R * HIST_S);       // 0: src, 1: dst
    int r = (b / HIST_S) % HIST_R;       // node range
    int s = b % HIST_S;                  // edge slice
    const int* arr = a ? dst : src;
    for (int i = threadIdx.x; i < LDSW; i += 256) hist[i] = 0;
    __syncthreads();
    int chunk = (E + HIST_S - 1) / HIST_S;
    int e0 = s * chunk;
    int e1 = min(e0 + chunk, E);
    unsigned base = (unsigned)(r * NPR);
    for (int i = e0 + threadIdx.x; i < e1; i += 256) {
        unsigned n = (unsigned)arr[i] - base;
        if (n < NPR) atomicAdd(&hist[n >> 1], 1u << ((n & 1) * 16));
    }
    __syncthreads();
    unsigned* outp = partial + ((size_t)(a * HIST_R + r) * HIST_S + s) * LDSW;
    for (int i = threadIdx.x; i < LDSW; i += 256) outp[i] = hist[i];
}

__global__ void k_hist_merge(const unsigned* __restrict__ partial,
                             float* __restrict__ ns, float* __restrict__ nd,
                             int* __restrict__ inc, int N) {
    int t = blockIdx.x * blockDim.x + threadIdx.x;
    const int total_w = HIST_R * LDSW;   // words per array
    if (t >= 2 * total_w) return;
    int a = t / total_w;
    int wg = t % total_w;
    int r = wg / LDSW;
    int w = wg % LDSW;
    const unsigned* p = partial + ((size_t)(a * HIST_R + r) * HIST_S) * LDSW + w;
    unsigned sum = 0;
#pragma unroll
    for (int s = 0; s < HIST_S; ++s) sum += p[(size_t)s * LDSW];
    int n0 = r * NPR + w * 2;
    int d0 = (int)(sum & 0xFFFFu);
    int d1 = (int)(sum >> 16);
    if (a == 0) {
        if (n0 < N)     ns[n0]     = rsqrtf(fmaxf((float)d0, 1.0f));
        if (n0 + 1 < N) ns[n0 + 1] = rsqrtf(fmaxf((float)d1, 1.0f));
    } else {
        if (n0 < N)     { nd[n0]     = rsqrtf(fmaxf((float)d0, 1.0f)); inc[n0]     = d0; }
        if (n0 + 1 < N) { nd[n0 + 1] = rsqrtf(fmaxf((float)d1, 1.0f)); inc[n0 + 1] = d1; }
    }
}

// ---------------------------------------------------------------- CSR row_ptr scan
__global__ void k_scan_partial(const int* __restrict__ inc, int* __restrict__ bsum, int N) {
    __shared__ int s[256];
    int i = blockIdx.x * 256 + threadIdx.x;
    int t = threadIdx.x;
    s[t] = (i < N) ? inc[i] : 0;
    __syncthreads();
    for (int off = 128; off > 0; off >>= 1) {
        if (t < off) s[t] += s[t + off];
        __syncthreads();
    }
    if (t == 0) bsum[blockIdx.x] = s[0];
}

__global__ void k_scan_top(int* __restrict__ bsum, int nb) {
    __shared__ int s[256];
    int t = threadIdx.x;
    int v = (t < nb) ? bsum[t] : 0;
    s[t] = v;
    __syncthreads();
    for (int off = 1; off < 256; off <<= 1) {
        int u = (t >= off) ? s[t - off] : 0;
        __syncthreads();
        s[t] += u;
        __syncthreads();
    }
    if (t < nb) bsum[t] = s[t] - v;  // exclusive
}

__global__ void k_scan_write(const int* __restrict__ inc, const int* __restrict__ bsum,
                             int* __restrict__ row_ptr, int N) {
    __shared__ int s[256];
    int i = blockIdx.x * 256 + threadIdx.x;
    int t = threadIdx.x;
    int v = (i < N) ? inc[i] : 0;
    s[t] = v;
    __syncthreads();
    for (int off = 1; off < 256; off <<= 1) {
        int u = (t >= off) ? s[t - off] : 0;
        __syncthreads();
        s[t] += u;
        __syncthreads();
    }
    int ex = bsum[blockIdx.x] + s[t] - v;  // global exclusive prefix
    if (i < N) row_ptr[i] = ex;
    if (i == N - 1) row_ptr[N] = ex + v;
}

// ---------------------------------------------------------------- per-slice cursors
// cur[(r*HIST_S+s)*NPR + n'] = row_ptr[node] + sum_{s'<s} dst_hist[r][s'][node]
__global__ void k_cursor(const unsigned* __restrict__ partial, const int* __restrict__ row_ptr,
                         int* __restrict__ cur, int N) {
    int t = blockIdx.x * blockDim.x + threadIdx.x;  // over HIST_R * LDSW words
    if (t >= HIST_R * LDSW) return;
    int r = t / LDSW;
    int w = t % LDSW;
    int n0 = r * NPR + 2 * w;
    const unsigned* p = partial + ((size_t)(HIST_R + r) * HIST_S) * LDSW + w;  // dst array (a=1)
    int run0 = (n0 < N) ? row_ptr[n0] : 0;
    int run1 = (n0 + 1 < N) ? row_ptr[n0 + 1] : 0;
    int* c = cur + (size_t)r * HIST_S * NPR + 2 * w;
#pragma unroll
    for (int s = 0; s < HIST_S; ++s) {
        c[(size_t)s * NPR + 0] = run0;
        c[(size_t)s * NPR + 1] = run1;
        unsigned hv = p[(size_t)s * LDSW];
        run0 += (int)(hv & 0xFFFFu);
        run1 += (int)(hv >> 16);
    }
}

// ---------------------------------------------------------------- CSR fill (LDS cursors)
__global__ __launch_bounds__(256) void k_fill2(const int* __restrict__ src,
                                               const int* __restrict__ dst,
                                               const int* __restrict__ cur,
                                               int* __restrict__ csr, int E) {
    __shared__ int lcur[NPR];   // 50 KB
    int r = blockIdx.x / HIST_S;
    int s = blockIdx.x % HIST_S;
    const int* cs = cur + (size_t)(r * HIST_S + s) * NPR;
    for (int i = threadIdx.x; i < NPR; i += 256) lcur[i] = cs[i];
    __syncthreads();
    int chunk = (E + HIST_S - 1) / HIST_S;
    int e0 = s * chunk;
    int e1 = min(e0 + chunk, E);
    unsigned base = (unsigned)(r * NPR);
    for (int i = e0 + threadIdx.x; i < e1; i += 256) {
        unsigned d = (unsigned)dst[i] - base;
        if (d < NPR) {
            int p = atomicAdd(&lcur[d], 1);   // LDS atomic
            csr[p] = src[i];
        }
    }
}

// ---------------------------------------------------------------- h -> fp16(h * ns)
__global__ void k_h2half(const float4* __restrict__ h, const float* __restrict__ ns,
                         uint2* __restrict__ A, int N) {
    int i = blockIdx.x * blockDim.x + threadIdx.x;  // N*32 float4s
    if (i < N * 32) {
        int n = i >> 5;
        float s = ns[n];
        float4 v = h[i];
        __half2 p0 = __floats2half2_rn(v.x * s, v.y * s);
        __half2 p1 = __floats2half2_rn(v.z * s, v.w * s);
        uint2 o;
        o.x = *(unsigned*)&p0;
        o.y = *(unsigned*)&p1;
        A[i] = o;
    }
}

// ---------------------------------------------------------------- aggregation (fp16 gather)
__global__ void k_agg(const uint2* __restrict__ A, const int* __restrict__ row_ptr,
                      const int* __restrict__ csr, const float* __restrict__ nd,
                      float* __restrict__ B, int N) {
    int gtid = blockIdx.x * blockDim.x + threadIdx.x;
    int node = gtid >> 6;
    int lane = threadIdx.x & 63;
    if (node >= N) return;
    int e0 = row_ptr[node];
    int e1 = row_ptr[node + 1];
    int half = lane >> 5;    // 0: even edge, 1: odd edge
    int l8 = lane & 31;      // 8-byte slot within 256B row
    float ax = 0.f, ay = 0.f, az = 0.f, aw = 0.f;

    auto acc4 = [&](uint2 u) {
        __half2 p0 = *(__half2*)&u.x;
        __half2 p1 = *(__half2*)&u.y;
        float2 f0 = __half22float2(p0);
        float2 f1 = __half22float2(p1);
        ax += f0.x; ay += f0.y; az += f1.x; aw += f1.y;
    };

    int e = e0;
    for (; e + 8 <= e1; e += 8) {
        int s0 = csr[e + half];
        int s1 = csr[e + 2 + half];
        int s2 = csr[e + 4 + half];
        int s3 = csr[e + 6 + half];
        uint2 u0 = A[(size_t)s0 * 32 + l8];
        uint2 u1 = A[(size_t)s1 * 32 + l8];
        uint2 u2 = A[(size_t)s2 * 32 + l8];
        uint2 u3 = A[(size_t)s3 * 32 + l8];
        acc4(u0); acc4(u1); acc4(u2); acc4(u3);
    }
    for (; e + 2 <= e1; e += 2) {
        int s0 = csr[e + half];
        acc4(A[(size_t)s0 * 32 + l8]);
    }
    if (e < e1 && half == 0) {   // odd remainder: lower half only
        int s0 = csr[e];
        acc4(A[(size_t)s0 * 32 + l8]);
    }

    ax += __shfl_xor(ax, 32);
    ay += __shfl_xor(ay, 32);
    az += __shfl_xor(az, 32);
    aw += __shfl_xor(aw, 32);

    if (half == 0) {
        float scale = nd[node];
        float4 o;
        o.x = ax * scale; o.y = ay * scale; o.z = az * scale; o.w = aw * scale;
        ((float4*)B)[(size_t)node * 32 + l8] = o;
    }
}

// ---------------------------------------------------------------- GEMM + bias + relu
template <bool HALF_OUT>
__global__ __launch_bounds__(256) void k_gemm(
    const float* __restrict__ Y, const float* __restrict__ W,
    const float* __restrict__ bias, const float* __restrict__ ns,
    void* __restrict__ Xout, int N) {
    __shared__ float xsT[32][36];   // [kk][row]
    __shared__ float ws[32][128];   // [kk][col]

    int tid = threadIdx.x;
    int tx = tid & 31;      // col group: cols 4*tx..4*tx+3
    int ty = tid >> 5;      // row group: rows ty*4..ty*4+3
    int r0 = blockIdx.x * 32;

    float acc[4][4] = {};

    for (int k0 = 0; k0 < 128; k0 += 32) {
        {
            int r = tid >> 3;       // 0..31
            int cq = tid & 7;       // 0..7
            int row = r0 + r;
            float4 v = make_float4(0.f, 0.f, 0.f, 0.f);
            if (row < N) v = *(const float4*)&Y[(size_t)row * DIM + k0 + cq * 4];
            xsT[cq * 4 + 0][r] = v.x;
            xsT[cq * 4 + 1][r] = v.y;
            xsT[cq * 4 + 2][r] = v.z;
            xsT[cq * 4 + 3][r] = v.w;
        }
#pragma unroll
        for (int j = 0; j < 4; ++j) {
            int idx = tid + j * 256;
            int row = idx >> 5;
            int cq = idx & 31;
            *(float4*)&ws[row][cq * 4] =
                *(const float4*)&W[(size_t)(k0 + row) * DIM + cq * 4];
        }
        __syncthreads();
#pragma unroll
        for (int kk = 0; kk < 32; ++kk) {
            float4 a = *(const float4*)&xsT[kk][ty * 4];
            float4 w = *(const float4*)&ws[kk][tx * 4];
            acc[0][0] += a.x * w.x; acc[0][1] += a.x * w.y; acc[0][2] += a.x * w.z; acc[0][3] += a.x * w.w;
            acc[1][0] += a.y * w.x; acc[1][1] += a.y * w.y; acc[1][2] += a.y * w.z; acc[1][3] += a.y * w.w;
            acc[2][0] += a.z * w.x; acc[2][1] += a.z * w.y; acc[2][2] += a.z * w.z; acc[2][3] += a.z * w.w;
            acc[3][0] += a.w * w.x; acc[3][1] += a.w * w.y; acc[3][2] += a.w * w.z; acc[3][3] += a.w * w.w;
        }
        __syncthreads();
    }

    float4 bb = *(const float4*)&bias[tx * 4];
#pragma unroll
    for (int i = 0; i < 4; ++i) {
        int row = r0 + ty * 4 + i;
        if (row >= N) continue;
        float o0 = fmaxf(acc[i][0] + bb.x, 0.0f);
        float o1 = fmaxf(acc[i][1] + bb.y, 0.0f);
        float o2 = fmaxf(acc[i][2] + bb.z, 0.0f);
        float o3 = fmaxf(acc[i][3] + bb.w, 0.0f);
        if (HALF_OUT) {
            float s = ns[row];
            __half2 p0 = __floats2half2_rn(o0 * s, o1 * s);
            __half2 p1 = __floats2half2_rn(o2 * s, o3 * s);
            uint2 o;
            o.x = *(unsigned*)&p0;
            o.y = *(unsigned*)&p1;
            ((uint2*)Xout)[(size_t)row * 32 + tx] = o;
        } else {
            float4 o = make_float4(o0, o1, o2, o3);
            ((float4*)Xout)[(size_t)row * 32 + tx] = o;
        }
    }
}

// ---------------------------------------------------------------- pooling
#define POOL_NODES 32
__global__ void k_pool_partial(const float* __restrict__ X, const int* __restrict__ gid,
                               float* __restrict__ gsum, int* __restrict__ gcnt, int N) {
    int n0 = blockIdx.x * POOL_NODES;
    int d = threadIdx.x;  // 0..127
    int nend = min(n0 + POOL_NODES, N);
    float run = 0.0f;
    int cnt = 0;
    int curg = -1;
    for (int n = n0; n < nend; ++n) {
        int g = gid[n];
        if (g != curg) {
            if (cnt > 0) {
                atomicAdd(&gsum[curg * DIM + d], run);
                if (d == 0) atomicAdd(&gcnt[curg], cnt);
            }
            run = 0.0f; cnt = 0; curg = g;
        }
        run += X[(size_t)n * DIM + d];
        cnt++;
    }
    if (cnt > 0) {
        atomicAdd(&gsum[curg * DIM + d], run);
        if (d == 0) atomicAdd(&gcnt[curg], cnt);
    }
}

__global__ void k_finalize(const float* __restrict__ gsum, const int* __restrict__ gcnt,
                           float* __restrict__ out, int G) {
    int i = blockIdx.x * blockDim.x + threadIdx.x;
    if (i < G * DIM) {
        int g = i >> 7;
        float c = fmaxf((float)gcnt[g], 1.0f);
        out[i] = gsum[i] / c;
    }
}

// ---------------------------------------------------------------- launch
extern "C" void kernel_launch(void* const* d_in, const int* in_sizes, int n_in,
                              void* d_out, int out_size, void* d_ws, size_t ws_size,
                              hipStream_t stream) {
    const float* h   = (const float*)d_in[0];
    const int*   src = (const int*)d_in[1];
    const int*   dst = (const int*)d_in[2];
    const int*   gid = (const int*)d_in[3];
    const float* W1  = (const float*)d_in[4];
    const float* b1  = (const float*)d_in[5];
    const float* W2  = (const float*)d_in[6];
    const float* b2  = (const float*)d_in[7];
    const float* W3  = (const float*)d_in[8];
    const float* b3  = (const float*)d_in[9];

    const int N = in_sizes[0] / DIM;   // 50000
    const int E = in_sizes[1];         // 600000
    const int G = 64;
    float* out = (float*)d_out;

    char* ws = (char*)d_ws;
    size_t off = 0;
    auto alloc = [&](size_t bytes) -> void* {
        void* p = ws + off;
        off += (bytes + 255) & ~(size_t)255;
        return p;
    };
    const int scanBlocks = (N + 255) / 256;
    uint2* Ah0     = (uint2*)alloc((size_t)N * DIM * 2);  // fp16 gather operand (ping)
    uint2* Ah1     = (uint2*)alloc((size_t)N * DIM * 2);  // fp16 pong
    float* B       = (float*)alloc((size_t)N * DIM * 4);  // agg output (fp32)
    float* X3      = (float*)alloc((size_t)N * DIM * 4);  // layer-3 fp32 output
    float* ns      = (float*)alloc((size_t)N * 4);
    float* nd      = (float*)alloc((size_t)N * 4);
    int*   inc     = (int*)alloc((size_t)N * 4);
    unsigned* partial = (unsigned*)alloc((size_t)2 * HIST_R * HIST_S * LDSW * 4);  // 12.8 MB
    int*   cur     = (int*)alloc((size_t)HIST_R * HIST_S * NPR * 4);               // 12.8 MB
    int*   row_ptr = (int*)alloc((size_t)(N + 1) * 4);
    int*   csr     = (int*)alloc((size_t)E * 4);
    float* gsum    = (float*)alloc((size_t)G * DIM * 4);
    int*   gcnt    = (int*)alloc((size_t)G * 4);
    int*   bsum    = (int*)alloc((size_t)scanBlocks * 4);

    hipMemsetAsync(gsum, 0, (size_t)G * DIM * 4, stream);
    hipMemsetAsync(gcnt, 0, (size_t)G * 4, stream);

    // degrees via LDS histograms (no global atomics)
    k_hist<<<2 * HIST_R * HIST_S, 256, 0, stream>>>(src, dst, partial, E);
    int mergeThreads = 2 * HIST_R * LDSW;
    k_hist_merge<<<(mergeThreads + 255) / 256, 256, 0, stream>>>(partial, ns, nd, inc, N);

    k_scan_partial<<<scanBlocks, 256, 0, stream>>>(inc, bsum, N);
    k_scan_top<<<1, 256, 0, stream>>>(bsum, scanBlocks);
    k_scan_write<<<scanBlocks, 256, 0, stream>>>(inc, bsum, row_ptr, N);

    // per-(range,slice) cursors from histogram prefix; CSR fill with LDS cursors
    int curThreads = HIST_R * LDSW;
    k_cursor<<<(curThreads + 255) / 256, 256, 0, stream>>>(partial, row_ptr, cur, N);
    k_fill2<<<HIST_R * HIST_S, 256, 0, stream>>>(src, dst, cur, csr, E);

    int aggBlocks  = (N * 64 + 255) / 256;
    int gemmBlocks = (N + 31) / 32;

    // layer 1: Ah0 = fp16(h * ns); agg; gemm -> Ah1 (fp16, *ns)
    k_h2half<<<(N * 32 + 255) / 256, 256, 0, stream>>>((const float4*)h, ns, Ah0, N);
    k_agg<<<aggBlocks, 256, 0, stream>>>(Ah0, row_ptr, csr, nd, B, N);
    k_gemm<true><<<gemmBlocks, 256, 0, stream>>>(B, W1, b1, ns, Ah1, N);
    // layer 2
    k_agg<<<aggBlocks, 256, 0, stream>>>(Ah1, row_ptr, csr, nd, B, N);
    k_gemm<true><<<gemmBlocks, 256, 0, stream>>>(B, W2, b2, ns, Ah0, N);
    // layer 3 (fp32 out, no ns)
    k_agg<<<aggBlocks, 256, 0, stream>>>(Ah0, row_ptr, csr, nd, B, N);
    k_gemm<false><<<gemmBlocks, 256, 0, stream>>>(B, W3, b3, ns, X3, N);

    k_pool_partial<<<(N + POOL_NODES - 1) / POOL_NODES, 128, 0, stream>>>(X3, gid, gsum, gcnt, N);
    k_finalize<<<(G * DIM + 255) / 256, 256, 0, stream>>>(gsum, gcnt, out, G);
}

// Round 10
// 325.924 us; speedup vs baseline: 1.3325x; 1.0310x over previous
//
#include <hip/hip_runtime.h>
#include <hip/hip_fp16.h>

// GraphEmbedding2: 3-layer GCN (DGL GraphConv, norm='both') + per-graph mean pooling.
// N=50000 nodes, E=600000 edges, d=128, G=64 graphs.
// fp16 gather operands (R6); LDS-histogram degrees + LDS-cursor CSR fill (R5/R8,
// zero global atomics); R9: GEMM on matrix cores (mfma_f32_16x16x32_f16, fp32 acc),
// agg output fp16. R7 fusion stays reverted (occupancy+bank-conflict lesson).

#define DIM 128

typedef _Float16 half8 __attribute__((ext_vector_type(8)));
typedef float floatx4 __attribute__((ext_vector_type(4)));

// ---------------------------------------------------------------- degree histogram (LDS)
#define HIST_R 4
#define HIST_S 64
#define NPR 12500          // nodes per range (HIST_R * NPR = 50000)
#define LDSW (NPR / 2)     // 6250 u32 words, 25 KB LDS

__global__ __launch_bounds__(256) void k_hist(const int* __restrict__ src,
                                              const int* __restrict__ dst,
                                              unsigned* __restrict__ partial, int E) {
    __shared__ unsigned hist[LDSW];
    int b = blockIdx.x;
    int a = b / (HIST_R * HIST_S);       // 0: src, 1: dst
    int r = (b / HIST_S) % HIST_R;       // node range
    int s = b % HIST_S;                  // edge slice
    const int* arr = a ? dst : src;
    for (int i = threadIdx.x; i < LDSW; i += 256) hist[i] = 0;
    __syncthreads();
    int chunk = (E + HIST_S - 1) / HIST_S;
    int e0 = s * chunk;
    int e1 = min(e0 + chunk, E);
    unsigned base = (unsigned)(r * NPR);
    for (int i = e0 + threadIdx.x; i < e1; i += 256) {
        unsigned n = (unsigned)arr[i] - base;
        if (n < NPR) atomicAdd(&hist[n >> 1], 1u << ((n & 1) * 16));
    }
    __syncthreads();
    unsigned* outp = partial + ((size_t)(a * HIST_R + r) * HIST_S + s) * LDSW;
    for (int i = threadIdx.x; i < LDSW; i += 256) outp[i] = hist[i];
}

__global__ void k_hist_merge(const unsigned* __restrict__ partial,
                             float* __restrict__ ns, float* __restrict__ nd,
                             int* __restrict__ inc, int N) {
    int t = blockIdx.x * blockDim.x + threadIdx.x;
    const int total_w = HIST_R * LDSW;   // words per array
    if (t >= 2 * total_w) return;
    int a = t / total_w;
    int wg = t % total_w;
    int r = wg / LDSW;
    int w = wg % LDSW;
    const unsigned* p = partial + ((size_t)(a * HIST_R + r) * HIST_S) * LDSW + w;
    unsigned sum = 0;
#pragma unroll
    for (int s = 0; s < HIST_S; ++s) sum += p[(size_t)s * LDSW];
    int n0 = r * NPR + w * 2;
    int d0 = (int)(sum & 0xFFFFu);
    int d1 = (int)(sum >> 16);
    if (a == 0) {
        if (n0 < N)     ns[n0]     = rsqrtf(fmaxf((float)d0, 1.0f));
        if (n0 + 1 < N) ns[n0 + 1] = rsqrtf(fmaxf((float)d1, 1.0f));
    } else {
        if (n0 < N)     { nd[n0]     = rsqrtf(fmaxf((float)d0, 1.0f)); inc[n0]     = d0; }
        if (n0 + 1 < N) { nd[n0 + 1] = rsqrtf(fmaxf((float)d1, 1.0f)); inc[n0 + 1] = d1; }
    }
}

// ---------------------------------------------------------------- CSR row_ptr scan
__global__ void k_scan_partial(const int* __restrict__ inc, int* __restrict__ bsum, int N) {
    __shared__ int s[256];
    int i = blockIdx.x * 256 + threadIdx.x;
    int t = threadIdx.x;
    s[t] = (i < N) ? inc[i] : 0;
    __syncthreads();
    for (int off = 128; off > 0; off >>= 1) {
        if (t < off) s[t] += s[t + off];
        __syncthreads();
    }
    if (t == 0) bsum[blockIdx.x] = s[0];
}

__global__ void k_scan_top(int* __restrict__ bsum, int nb) {
    __shared__ int s[256];
    int t = threadIdx.x;
    int v = (t < nb) ? bsum[t] : 0;
    s[t] = v;
    __syncthreads();
    for (int off = 1; off < 256; off <<= 1) {
        int u = (t >= off) ? s[t - off] : 0;
        __syncthreads();
        s[t] += u;
        __syncthreads();
    }
    if (t < nb) bsum[t] = s[t] - v;  // exclusive
}

__global__ void k_scan_write(const int* __restrict__ inc, const int* __restrict__ bsum,
                             int* __restrict__ row_ptr, int N) {
    __shared__ int s[256];
    int i = blockIdx.x * 256 + threadIdx.x;
    int t = threadIdx.x;
    int v = (i < N) ? inc[i] : 0;
    s[t] = v;
    __syncthreads();
    for (int off = 1; off < 256; off <<= 1) {
        int u = (t >= off) ? s[t - off] : 0;
        __syncthreads();
        s[t] += u;
        __syncthreads();
    }
    int ex = bsum[blockIdx.x] + s[t] - v;  // global exclusive prefix
    if (i < N) row_ptr[i] = ex;
    if (i == N - 1) row_ptr[N] = ex + v;
}

// ---------------------------------------------------------------- per-slice cursors
__global__ void k_cursor(const unsigned* __restrict__ partial, const int* __restrict__ row_ptr,
                         int* __restrict__ cur, int N) {
    int t = blockIdx.x * blockDim.x + threadIdx.x;  // over HIST_R * LDSW words
    if (t >= HIST_R * LDSW) return;
    int r = t / LDSW;
    int w = t % LDSW;
    int n0 = r * NPR + 2 * w;
    const unsigned* p = partial + ((size_t)(HIST_R + r) * HIST_S) * LDSW + w;  // dst (a=1)
    int run0 = (n0 < N) ? row_ptr[n0] : 0;
    int run1 = (n0 + 1 < N) ? row_ptr[n0 + 1] : 0;
    int* c = cur + (size_t)r * HIST_S * NPR + 2 * w;
#pragma unroll
    for (int s = 0; s < HIST_S; ++s) {
        c[(size_t)s * NPR + 0] = run0;
        c[(size_t)s * NPR + 1] = run1;
        unsigned hv = p[(size_t)s * LDSW];
        run0 += (int)(hv & 0xFFFFu);
        run1 += (int)(hv >> 16);
    }
}

// ---------------------------------------------------------------- CSR fill (LDS cursors)
__global__ __launch_bounds__(256) void k_fill2(const int* __restrict__ src,
                                               const int* __restrict__ dst,
                                               const int* __restrict__ cur,
                                               int* __restrict__ csr, int E) {
    __shared__ int lcur[NPR];   // 50 KB
    int r = blockIdx.x / HIST_S;
    int s = blockIdx.x % HIST_S;
    const int* cs = cur + (size_t)(r * HIST_S + s) * NPR;
    for (int i = threadIdx.x; i < NPR; i += 256) lcur[i] = cs[i];
    __syncthreads();
    int chunk = (E + HIST_S - 1) / HIST_S;
    int e0 = s * chunk;
    int e1 = min(e0 + chunk, E);
    unsigned base = (unsigned)(r * NPR);
    for (int i = e0 + threadIdx.x; i < e1; i += 256) {
        unsigned d = (unsigned)dst[i] - base;
        if (d < NPR) {
            int p = atomicAdd(&lcur[d], 1);   // LDS atomic
            csr[p] = src[i];
        }
    }
}

// ---------------------------------------------------------------- h -> fp16(h * ns)
__global__ void k_h2half(const float4* __restrict__ h, const float* __restrict__ ns,
                         uint2* __restrict__ A, int N) {
    int i = blockIdx.x * blockDim.x + threadIdx.x;  // N*32 float4s
    if (i < N * 32) {
        int n = i >> 5;
        float s = ns[n];
        float4 v = h[i];
        __half2 p0 = __floats2half2_rn(v.x * s, v.y * s);
        __half2 p1 = __floats2half2_rn(v.z * s, v.w * s);
        uint2 o;
        o.x = *(unsigned*)&p0;
        o.y = *(unsigned*)&p1;
        A[i] = o;
    }
}

// ---------------------------------------------------------------- W -> fp16 transposed
// Wt[n][k] = W[k][n]; B-fragment (B[k=quad*8+j][n=l16]) then loads 16B contiguous.
__global__ void k_w2half(const float* __restrict__ W, _Float16* __restrict__ Wt) {
    int i = blockIdx.x * blockDim.x + threadIdx.x;  // 16384
    int k = i >> 7;
    int n = i & 127;
    Wt[(size_t)n * DIM + k] = (_Float16)W[i];
}

// ---------------------------------------------------------------- aggregation (fp16 gather, fp16 out)
__global__ void k_agg(const uint2* __restrict__ A, const int* __restrict__ row_ptr,
                      const int* __restrict__ csr, const float* __restrict__ nd,
                      uint2* __restrict__ Bh, int N) {
    int gtid = blockIdx.x * blockDim.x + threadIdx.x;
    int node = gtid >> 6;
    int lane = threadIdx.x & 63;
    if (node >= N) return;
    int e0 = row_ptr[node];
    int e1 = row_ptr[node + 1];
    int half = lane >> 5;    // 0: even edge, 1: odd edge
    int l8 = lane & 31;      // 8-byte slot within 256B row
    float ax = 0.f, ay = 0.f, az = 0.f, aw = 0.f;

    auto acc4 = [&](uint2 u) {
        __half2 p0 = *(__half2*)&u.x;
        __half2 p1 = *(__half2*)&u.y;
        float2 f0 = __half22float2(p0);
        float2 f1 = __half22float2(p1);
        ax += f0.x; ay += f0.y; az += f1.x; aw += f1.y;
    };

    int e = e0;
    for (; e + 8 <= e1; e += 8) {
        int s0 = csr[e + half];
        int s1 = csr[e + 2 + half];
        int s2 = csr[e + 4 + half];
        int s3 = csr[e + 6 + half];
        uint2 u0 = A[(size_t)s0 * 32 + l8];
        uint2 u1 = A[(size_t)s1 * 32 + l8];
        uint2 u2 = A[(size_t)s2 * 32 + l8];
        uint2 u3 = A[(size_t)s3 * 32 + l8];
        acc4(u0); acc4(u1); acc4(u2); acc4(u3);
    }
    for (; e + 2 <= e1; e += 2) {
        int s0 = csr[e + half];
        acc4(A[(size_t)s0 * 32 + l8]);
    }
    if (e < e1 && half == 0) {   // odd remainder: lower half only
        int s0 = csr[e];
        acc4(A[(size_t)s0 * 32 + l8]);
    }

    ax += __shfl_xor(ax, 32);
    ay += __shfl_xor(ay, 32);
    az += __shfl_xor(az, 32);
    aw += __shfl_xor(aw, 32);

    if (half == 0) {
        float scale = nd[node];
        __half2 p0 = __floats2half2_rn(ax * scale, ay * scale);
        __half2 p1 = __floats2half2_rn(az * scale, aw * scale);
        uint2 o;
        o.x = *(unsigned*)&p0;
        o.y = *(unsigned*)&p1;
        Bh[(size_t)node * 32 + l8] = o;
    }
}

// ---------------------------------------------------------------- GEMM on matrix cores
// X = relu(Bin @ W + b). Bin fp16 [N][128], Wt fp16 [n][k]. 4 waves x 16 rows = 64 rows/block.
// Fragments (16x16x32 f16): A: lane=A[m=l16][k=quad*8+j]; B: lane=B[k=quad*8+j][n=l16];
// C/D: col=l16, row=quad*4+reg (m89/m91-verified, dtype-independent).
// HALF_OUT: store fp16(x * ns) (next layer's gather operand), else fp32.
template <bool HALF_OUT>
__global__ __launch_bounds__(256) void k_gemm_mfma(
    const _Float16* __restrict__ Bin, const _Float16* __restrict__ Wt,
    const float* __restrict__ bias, const float* __restrict__ ns,
    void* __restrict__ Xout, int N) {
    int tid = threadIdx.x;
    int wave = tid >> 6;
    int lane = tid & 63;
    int quad = lane >> 4;
    int l16 = lane & 15;
    int r0 = blockIdx.x * 64 + wave * 16;
    int arow = r0 + l16;

    half8 a[4];
#pragma unroll
    for (int q = 0; q < 4; ++q) {
        if (arow < N) {
            a[q] = *(const half8*)&Bin[(size_t)arow * DIM + q * 32 + quad * 8];
        } else {
            a[q] = half8{0, 0, 0, 0, 0, 0, 0, 0};
        }
    }

    floatx4 acc[8];
#pragma unroll
    for (int c = 0; c < 8; ++c) acc[c] = floatx4{0.f, 0.f, 0.f, 0.f};

#pragma unroll
    for (int c = 0; c < 8; ++c) {
#pragma unroll
        for (int q = 0; q < 4; ++q) {
            half8 b = *(const half8*)&Wt[(size_t)(c * 16 + l16) * DIM + q * 32 + quad * 8];
            acc[c] = __builtin_amdgcn_mfma_f32_16x16x32_f16(a[q], b, acc[c], 0, 0, 0);
        }
    }

    float bb[8];
#pragma unroll
    for (int c = 0; c < 8; ++c) bb[c] = bias[c * 16 + l16];

#pragma unroll
    for (int r = 0; r < 4; ++r) {
        int row = r0 + quad * 4 + r;
        if (row >= N) continue;
        float sr = HALF_OUT ? ns[row] : 1.0f;
#pragma unroll
        for (int c = 0; c < 8; ++c) {
            float v = fmaxf(acc[c][r] + bb[c], 0.0f);
            if (HALF_OUT) {
                ((_Float16*)Xout)[(size_t)row * DIM + c * 16 + l16] = (_Float16)(v * sr);
            } else {
                ((float*)Xout)[(size_t)row * DIM + c * 16 + l16] = v;
            }
        }
    }
}

// ---------------------------------------------------------------- pooling
#define POOL_NODES 32
__global__ void k_pool_partial(const float* __restrict__ X, const int* __restrict__ gid,
                               float* __restrict__ gsum, int* __restrict__ gcnt, int N) {
    int n0 = blockIdx.x * POOL_NODES;
    int d = threadIdx.x;  // 0..127
    int nend = min(n0 + POOL_NODES, N);
    float run = 0.0f;
    int cnt = 0;
    int curg = -1;
    for (int n = n0; n < nend; ++n) {
        int g = gid[n];
        if (g != curg) {
            if (cnt > 0) {
                atomicAdd(&gsum[curg * DIM + d], run);
                if (d == 0) atomicAdd(&gcnt[curg], cnt);
            }
            run = 0.0f; cnt = 0; curg = g;
        }
        run += X[(size_t)n * DIM + d];
        cnt++;
    }
    if (cnt > 0) {
        atomicAdd(&gsum[curg * DIM + d], run);
        if (d == 0) atomicAdd(&gcnt[curg], cnt);
    }
}

__global__ void k_finalize(const float* __restrict__ gsum, const int* __restrict__ gcnt,
                           float* __restrict__ out, int G) {
    int i = blockIdx.x * blockDim.x + threadIdx.x;
    if (i < G * DIM) {
        int g = i >> 7;
        float c = fmaxf((float)gcnt[g], 1.0f);
        out[i] = gsum[i] / c;
    }
}

// ---------------------------------------------------------------- launch
extern "C" void kernel_launch(void* const* d_in, const int* in_sizes, int n_in,
                              void* d_out, int out_size, void* d_ws, size_t ws_size,
                              hipStream_t stream) {
    const float* h   = (const float*)d_in[0];
    const int*   src = (const int*)d_in[1];
    const int*   dst = (const int*)d_in[2];
    const int*   gid = (const int*)d_in[3];
    const float* W1  = (const float*)d_in[4];
    const float* b1  = (const float*)d_in[5];
    const float* W2  = (const float*)d_in[6];
    const float* b2  = (const float*)d_in[7];
    const float* W3  = (const float*)d_in[8];
    const float* b3  = (const float*)d_in[9];

    const int N = in_sizes[0] / DIM;   // 50000
    const int E = in_sizes[1];         // 600000
    const int G = 64;
    float* out = (float*)d_out;

    char* ws = (char*)d_ws;
    size_t off = 0;
    auto alloc = [&](size_t bytes) -> void* {
        void* p = ws + off;
        off += (bytes + 255) & ~(size_t)255;
        return p;
    };
    const int scanBlocks = (N + 255) / 256;
    uint2* Ah0     = (uint2*)alloc((size_t)N * DIM * 2);  // fp16 gather operand (ping)
    uint2* Ah1     = (uint2*)alloc((size_t)N * DIM * 2);  // fp16 pong
    uint2* Bh      = (uint2*)alloc((size_t)N * DIM * 2);  // agg output (fp16)
    float* X3      = (float*)alloc((size_t)N * DIM * 4);  // layer-3 fp32 output
    _Float16* Wt1  = (_Float16*)alloc((size_t)DIM * DIM * 2);
    _Float16* Wt2  = (_Float16*)alloc((size_t)DIM * DIM * 2);
    _Float16* Wt3  = (_Float16*)alloc((size_t)DIM * DIM * 2);
    float* ns      = (float*)alloc((size_t)N * 4);
    float* nd      = (float*)alloc((size_t)N * 4);
    int*   inc     = (int*)alloc((size_t)N * 4);
    unsigned* partial = (unsigned*)alloc((size_t)2 * HIST_R * HIST_S * LDSW * 4);  // 12.8 MB
    int*   cur     = (int*)alloc((size_t)HIST_R * HIST_S * NPR * 4);               // 12.8 MB
    int*   row_ptr = (int*)alloc((size_t)(N + 1) * 4);
    int*   csr     = (int*)alloc((size_t)E * 4);
    float* gsum    = (float*)alloc((size_t)G * DIM * 4);
    int*   gcnt    = (int*)alloc((size_t)G * 4);
    int*   bsum    = (int*)alloc((size_t)scanBlocks * 4);

    hipMemsetAsync(gsum, 0, (size_t)G * DIM * 4, stream);
    hipMemsetAsync(gcnt, 0, (size_t)G * 4, stream);

    // degrees via LDS histograms (no global atomics)
    k_hist<<<2 * HIST_R * HIST_S, 256, 0, stream>>>(src, dst, partial, E);
    int mergeThreads = 2 * HIST_R * LDSW;
    k_hist_merge<<<(mergeThreads + 255) / 256, 256, 0, stream>>>(partial, ns, nd, inc, N);

    k_scan_partial<<<scanBlocks, 256, 0, stream>>>(inc, bsum, N);
    k_scan_top<<<1, 256, 0, stream>>>(bsum, scanBlocks);
    k_scan_write<<<scanBlocks, 256, 0, stream>>>(inc, bsum, row_ptr, N);

    // per-(range,slice) cursors from histogram prefix; CSR fill with LDS cursors
    int curThreads = HIST_R * LDSW;
    k_cursor<<<(curThreads + 255) / 256, 256, 0, stream>>>(partial, row_ptr, cur, N);
    k_fill2<<<HIST_R * HIST_S, 256, 0, stream>>>(src, dst, cur, csr, E);

    // weights -> fp16 transposed
    k_w2half<<<64, 256, 0, stream>>>(W1, Wt1);
    k_w2half<<<64, 256, 0, stream>>>(W2, Wt2);
    k_w2half<<<64, 256, 0, stream>>>(W3, Wt3);

    int aggBlocks  = (N * 64 + 255) / 256;
    int gemmBlocks = (N + 63) / 64;

    // layer 1: Ah0 = fp16(h * ns); agg -> Bh (fp16); mfma gemm -> Ah1 (fp16, *ns)
    k_h2half<<<(N * 32 + 255) / 256, 256, 0, stream>>>((const float4*)h, ns, Ah0, N);
    k_agg<<<aggBlocks, 256, 0, stream>>>(Ah0, row_ptr, csr, nd, Bh, N);
    k_gemm_mfma<true><<<gemmBlocks, 256, 0, stream>>>((const _Float16*)Bh, Wt1, b1, ns, Ah1, N);
    // layer 2
    k_agg<<<aggBlocks, 256, 0, stream>>>(Ah1, row_ptr, csr, nd, Bh, N);
    k_gemm_mfma<true><<<gemmBlocks, 256, 0, stream>>>((const _Float16*)Bh, Wt2, b2, ns, Ah0, N);
    // layer 3 (fp32 out, no ns)
    k_agg<<<aggBlocks, 256, 0, stream>>>(Ah0, row_ptr, csr, nd, Bh, N);
    k_gemm_mfma<false><<<gemmBlocks, 256, 0, stream>>>((const _Float16*)Bh, Wt3, b3, ns, X3, N);

    k_pool_partial<<<(N + POOL_NODES - 1) / POOL_NODES, 128, 0, stream>>>(X3, gid, gsum, gcnt, N);
    k_finalize<<<(G * DIM + 255) / 256, 256, 0, stream>>>(gsum, gcnt, out, G);
}

// Round 11
// 317.774 us; speedup vs baseline: 1.3667x; 1.0256x over previous
//
#include <hip/hip_runtime.h>
#include <hip/hip_fp16.h>

// GraphEmbedding2: 3-layer GCN (DGL GraphConv, norm='both') + per-graph mean pooling.
// N=50000 nodes, E=600000 edges, d=128, G=64 graphs.
// fp16 gather operands (R6); LDS-histogram degrees + LDS-cursor CSR fill (R5/R8,
// zero global atomics); MFMA GEMM fp16-in/fp32-acc (R9).
// R10: agg issues one clamped 16-edge round (8 gathers in flight/lane, predicated
// accumulate) to double memory-level parallelism; w2half merged to 1 launch;
// layer-3 output + pooling fp16.

#define DIM 128

typedef _Float16 half8 __attribute__((ext_vector_type(8)));
typedef float floatx4 __attribute__((ext_vector_type(4)));

// ---------------------------------------------------------------- degree histogram (LDS)
#define HIST_R 4
#define HIST_S 64
#define NPR 12500          // nodes per range (HIST_R * NPR = 50000)
#define LDSW (NPR / 2)     // 6250 u32 words, 25 KB LDS

__global__ __launch_bounds__(256) void k_hist(const int* __restrict__ src,
                                              const int* __restrict__ dst,
                                              unsigned* __restrict__ partial, int E) {
    __shared__ unsigned hist[LDSW];
    int b = blockIdx.x;
    int a = b / (HIST_R * HIST_S);       // 0: src, 1: dst
    int r = (b / HIST_S) % HIST_R;       // node range
    int s = b % HIST_S;                  // edge slice
    const int* arr = a ? dst : src;
    for (int i = threadIdx.x; i < LDSW; i += 256) hist[i] = 0;
    __syncthreads();
    int chunk = (E + HIST_S - 1) / HIST_S;
    int e0 = s * chunk;
    int e1 = min(e0 + chunk, E);
    unsigned base = (unsigned)(r * NPR);
    for (int i = e0 + threadIdx.x; i < e1; i += 256) {
        unsigned n = (unsigned)arr[i] - base;
        if (n < NPR) atomicAdd(&hist[n >> 1], 1u << ((n & 1) * 16));
    }
    __syncthreads();
    unsigned* outp = partial + ((size_t)(a * HIST_R + r) * HIST_S + s) * LDSW;
    for (int i = threadIdx.x; i < LDSW; i += 256) outp[i] = hist[i];
}

__global__ void k_hist_merge(const unsigned* __restrict__ partial,
                             float* __restrict__ ns, float* __restrict__ nd,
                             int* __restrict__ inc, int N) {
    int t = blockIdx.x * blockDim.x + threadIdx.x;
    const int total_w = HIST_R * LDSW;   // words per array
    if (t >= 2 * total_w) return;
    int a = t / total_w;
    int wg = t % total_w;
    int r = wg / LDSW;
    int w = wg % LDSW;
    const unsigned* p = partial + ((size_t)(a * HIST_R + r) * HIST_S) * LDSW + w;
    unsigned sum = 0;
#pragma unroll
    for (int s = 0; s < HIST_S; ++s) sum += p[(size_t)s * LDSW];
    int n0 = r * NPR + w * 2;
    int d0 = (int)(sum & 0xFFFFu);
    int d1 = (int)(sum >> 16);
    if (a == 0) {
        if (n0 < N)     ns[n0]     = rsqrtf(fmaxf((float)d0, 1.0f));
        if (n0 + 1 < N) ns[n0 + 1] = rsqrtf(fmaxf((float)d1, 1.0f));
    } else {
        if (n0 < N)     { nd[n0]     = rsqrtf(fmaxf((float)d0, 1.0f)); inc[n0]     = d0; }
        if (n0 + 1 < N) { nd[n0 + 1] = rsqrtf(fmaxf((float)d1, 1.0f)); inc[n0 + 1] = d1; }
    }
}

// ---------------------------------------------------------------- CSR row_ptr scan
__global__ void k_scan_partial(const int* __restrict__ inc, int* __restrict__ bsum, int N) {
    __shared__ int s[256];
    int i = blockIdx.x * 256 + threadIdx.x;
    int t = threadIdx.x;
    s[t] = (i < N) ? inc[i] : 0;
    __syncthreads();
    for (int off = 128; off > 0; off >>= 1) {
        if (t < off) s[t] += s[t + off];
        __syncthreads();
    }
    if (t == 0) bsum[blockIdx.x] = s[0];
}

__global__ void k_scan_top(int* __restrict__ bsum, int nb) {
    __shared__ int s[256];
    int t = threadIdx.x;
    int v = (t < nb) ? bsum[t] : 0;
    s[t] = v;
    __syncthreads();
    for (int off = 1; off < 256; off <<= 1) {
        int u = (t >= off) ? s[t - off] : 0;
        __syncthreads();
        s[t] += u;
        __syncthreads();
    }
    if (t < nb) bsum[t] = s[t] - v;  // exclusive
}

__global__ void k_scan_write(const int* __restrict__ inc, const int* __restrict__ bsum,
                             int* __restrict__ row_ptr, int N) {
    __shared__ int s[256];
    int i = blockIdx.x * 256 + threadIdx.x;
    int t = threadIdx.x;
    int v = (i < N) ? inc[i] : 0;
    s[t] = v;
    __syncthreads();
    for (int off = 1; off < 256; off <<= 1) {
        int u = (t >= off) ? s[t - off] : 0;
        __syncthreads();
        s[t] += u;
        __syncthreads();
    }
    int ex = bsum[blockIdx.x] + s[t] - v;  // global exclusive prefix
    if (i < N) row_ptr[i] = ex;
    if (i == N - 1) row_ptr[N] = ex + v;
}

// ---------------------------------------------------------------- per-slice cursors
__global__ void k_cursor(const unsigned* __restrict__ partial, const int* __restrict__ row_ptr,
                         int* __restrict__ cur, int N) {
    int t = blockIdx.x * blockDim.x + threadIdx.x;  // over HIST_R * LDSW words
    if (t >= HIST_R * LDSW) return;
    int r = t / LDSW;
    int w = t % LDSW;
    int n0 = r * NPR + 2 * w;
    const unsigned* p = partial + ((size_t)(HIST_R + r) * HIST_S) * LDSW + w;  // dst (a=1)
    int run0 = (n0 < N) ? row_ptr[n0] : 0;
    int run1 = (n0 + 1 < N) ? row_ptr[n0 + 1] : 0;
    int* c = cur + (size_t)r * HIST_S * NPR + 2 * w;
#pragma unroll
    for (int s = 0; s < HIST_S; ++s) {
        c[(size_t)s * NPR + 0] = run0;
        c[(size_t)s * NPR + 1] = run1;
        unsigned hv = p[(size_t)s * LDSW];
        run0 += (int)(hv & 0xFFFFu);
        run1 += (int)(hv >> 16);
    }
}

// ---------------------------------------------------------------- CSR fill (LDS cursors)
__global__ __launch_bounds__(256) void k_fill2(const int* __restrict__ src,
                                               const int* __restrict__ dst,
                                               const int* __restrict__ cur,
                                               int* __restrict__ csr, int E) {
    __shared__ int lcur[NPR];   // 50 KB
    int r = blockIdx.x / HIST_S;
    int s = blockIdx.x % HIST_S;
    const int* cs = cur + (size_t)(r * HIST_S + s) * NPR;
    for (int i = threadIdx.x; i < NPR; i += 256) lcur[i] = cs[i];
    __syncthreads();
    int chunk = (E + HIST_S - 1) / HIST_S;
    int e0 = s * chunk;
    int e1 = min(e0 + chunk, E);
    unsigned base = (unsigned)(r * NPR);
    for (int i = e0 + threadIdx.x; i < e1; i += 256) {
        unsigned d = (unsigned)dst[i] - base;
        if (d < NPR) {
            int p = atomicAdd(&lcur[d], 1);   // LDS atomic
            csr[p] = src[i];
        }
    }
}

// ---------------------------------------------------------------- h -> fp16(h * ns)
__global__ void k_h2half(const float4* __restrict__ h, const float* __restrict__ ns,
                         uint2* __restrict__ A, int N) {
    int i = blockIdx.x * blockDim.x + threadIdx.x;  // N*32 float4s
    if (i < N * 32) {
        int n = i >> 5;
        float s = ns[n];
        float4 v = h[i];
        __half2 p0 = __floats2half2_rn(v.x * s, v.y * s);
        __half2 p1 = __floats2half2_rn(v.z * s, v.w * s);
        uint2 o;
        o.x = *(unsigned*)&p0;
        o.y = *(unsigned*)&p1;
        A[i] = o;
    }
}

// ---------------------------------------------------------------- W1..W3 -> fp16 transposed (one launch)
__global__ void k_w2half3(const float* __restrict__ W1, const float* __restrict__ W2,
                          const float* __restrict__ W3, _Float16* __restrict__ Wt1,
                          _Float16* __restrict__ Wt2, _Float16* __restrict__ Wt3) {
    int i = blockIdx.x * blockDim.x + threadIdx.x;  // 3 * 16384
    int j = i >> 14;
    int local = i & 16383;
    int k = local >> 7;
    int n = local & 127;
    const float* W = (j == 0) ? W1 : (j == 1) ? W2 : W3;
    _Float16* Wt = (j == 0) ? Wt1 : (j == 1) ? Wt2 : Wt3;
    Wt[(size_t)n * DIM + k] = (_Float16)W[local];
}

// ---------------------------------------------------------------- aggregation
// One wave per node, paired edges (lanes 0-31: even, 32-63: odd). Single clamped
// 16-edge round: 8 gathers in flight per lane, indices clamped to e1-1 (legal),
// accumulation predicated on e < e1 (R10: MLP 4->8, chain 3 rounds -> 1).
__global__ __launch_bounds__(256) void k_agg(const uint2* __restrict__ A,
                                             const int* __restrict__ row_ptr,
                                             const int* __restrict__ csr,
                                             const float* __restrict__ nd,
                                             uint2* __restrict__ Bh, int N) {
    int gtid = blockIdx.x * blockDim.x + threadIdx.x;
    int node = gtid >> 6;
    int lane = threadIdx.x & 63;
    if (node >= N) return;
    int e0 = row_ptr[node];
    int e1 = row_ptr[node + 1];
    int half = lane >> 5;    // 0: even edge, 1: odd edge
    int l8 = lane & 31;      // 8-byte slot within 256B row
    float ax = 0.f, ay = 0.f, az = 0.f, aw = 0.f;

    for (int base = e0; base < e1; base += 16) {
        int idx[8];
        uint2 u[8];
#pragma unroll
        for (int j = 0; j < 8; ++j) {
            int ee = base + 2 * j + half;
            idx[j] = csr[min(ee, e1 - 1)];
        }
#pragma unroll
        for (int j = 0; j < 8; ++j) {
            u[j] = A[(size_t)idx[j] * 32 + l8];
        }
#pragma unroll
        for (int j = 0; j < 8; ++j) {
            int ee = base + 2 * j + half;
            if (ee < e1) {
                __half2 p0 = *(__half2*)&u[j].x;
                __half2 p1 = *(__half2*)&u[j].y;
                float2 f0 = __half22float2(p0);
                float2 f1 = __half22float2(p1);
                ax += f0.x; ay += f0.y; az += f1.x; aw += f1.y;
            }
        }
    }

    ax += __shfl_xor(ax, 32);
    ay += __shfl_xor(ay, 32);
    az += __shfl_xor(az, 32);
    aw += __shfl_xor(aw, 32);

    if (half == 0) {
        float scale = nd[node];
        __half2 p0 = __floats2half2_rn(ax * scale, ay * scale);
        __half2 p1 = __floats2half2_rn(az * scale, aw * scale);
        uint2 o;
        o.x = *(unsigned*)&p0;
        o.y = *(unsigned*)&p1;
        Bh[(size_t)node * 32 + l8] = o;
    }
}

// ---------------------------------------------------------------- GEMM on matrix cores
// X = relu(Bin @ W + b). Bin fp16 [N][128], Wt fp16 [n][k]. 4 waves x 16 rows = 64 rows/block.
// A: lane=A[m=l16][k=quad*8+j]; B: lane=B[k=quad*8+j][n=l16]; C/D: col=l16, row=quad*4+reg.
// Output always fp16; SCALE_NS multiplies rows by ns (layers 1-2).
template <bool SCALE_NS>
__global__ __launch_bounds__(256) void k_gemm_mfma(
    const _Float16* __restrict__ Bin, const _Float16* __restrict__ Wt,
    const float* __restrict__ bias, const float* __restrict__ ns,
    _Float16* __restrict__ Xout, int N) {
    int tid = threadIdx.x;
    int wave = tid >> 6;
    int lane = tid & 63;
    int quad = lane >> 4;
    int l16 = lane & 15;
    int r0 = blockIdx.x * 64 + wave * 16;
    int arow = r0 + l16;

    half8 a[4];
#pragma unroll
    for (int q = 0; q < 4; ++q) {
        if (arow < N) {
            a[q] = *(const half8*)&Bin[(size_t)arow * DIM + q * 32 + quad * 8];
        } else {
            a[q] = half8{0, 0, 0, 0, 0, 0, 0, 0};
        }
    }

    floatx4 acc[8];
#pragma unroll
    for (int c = 0; c < 8; ++c) acc[c] = floatx4{0.f, 0.f, 0.f, 0.f};

#pragma unroll
    for (int c = 0; c < 8; ++c) {
#pragma unroll
        for (int q = 0; q < 4; ++q) {
            half8 b = *(const half8*)&Wt[(size_t)(c * 16 + l16) * DIM + q * 32 + quad * 8];
            acc[c] = __builtin_amdgcn_mfma_f32_16x16x32_f16(a[q], b, acc[c], 0, 0, 0);
        }
    }

    float bb[8];
#pragma unroll
    for (int c = 0; c < 8; ++c) bb[c] = bias[c * 16 + l16];

#pragma unroll
    for (int r = 0; r < 4; ++r) {
        int row = r0 + quad * 4 + r;
        if (row >= N) continue;
        float sr = SCALE_NS ? ns[row] : 1.0f;
#pragma unroll
        for (int c = 0; c < 8; ++c) {
            float v = fmaxf(acc[c][r] + bb[c], 0.0f);
            Xout[(size_t)row * DIM + c * 16 + l16] = (_Float16)(v * sr);
        }
    }
}

// ---------------------------------------------------------------- pooling (fp16 input)
#define POOL_NODES 32
__global__ void k_pool_partial(const _Float16* __restrict__ X, const int* __restrict__ gid,
                               float* __restrict__ gsum, int* __restrict__ gcnt, int N) {
    int n0 = blockIdx.x * POOL_NODES;
    int d = threadIdx.x;  // 0..127
    int nend = min(n0 + POOL_NODES, N);
    float run = 0.0f;
    int cnt = 0;
    int curg = -1;
    for (int n = n0; n < nend; ++n) {
        int g = gid[n];
        if (g != curg) {
            if (cnt > 0) {
                atomicAdd(&gsum[curg * DIM + d], run);
                if (d == 0) atomicAdd(&gcnt[curg], cnt);
            }
            run = 0.0f; cnt = 0; curg = g;
        }
        run += (float)X[(size_t)n * DIM + d];
        cnt++;
    }
    if (cnt > 0) {
        atomicAdd(&gsum[curg * DIM + d], run);
        if (d == 0) atomicAdd(&gcnt[curg], cnt);
    }
}

__global__ void k_finalize(const float* __restrict__ gsum, const int* __restrict__ gcnt,
                           float* __restrict__ out, int G) {
    int i = blockIdx.x * blockDim.x + threadIdx.x;
    if (i < G * DIM) {
        int g = i >> 7;
        float c = fmaxf((float)gcnt[g], 1.0f);
        out[i] = gsum[i] / c;
    }
}

// ---------------------------------------------------------------- launch
extern "C" void kernel_launch(void* const* d_in, const int* in_sizes, int n_in,
                              void* d_out, int out_size, void* d_ws, size_t ws_size,
                              hipStream_t stream) {
    const float* h   = (const float*)d_in[0];
    const int*   src = (const int*)d_in[1];
    const int*   dst = (const int*)d_in[2];
    const int*   gid = (const int*)d_in[3];
    const float* W1  = (const float*)d_in[4];
    const float* b1  = (const float*)d_in[5];
    const float* W2  = (const float*)d_in[6];
    const float* b2  = (const float*)d_in[7];
    const float* W3  = (const float*)d_in[8];
    const float* b3  = (const float*)d_in[9];

    const int N = in_sizes[0] / DIM;   // 50000
    const int E = in_sizes[1];         // 600000
    const int G = 64;
    float* out = (float*)d_out;

    char* ws = (char*)d_ws;
    size_t off = 0;
    auto alloc = [&](size_t bytes) -> void* {
        void* p = ws + off;
        off += (bytes + 255) & ~(size_t)255;
        return p;
    };
    const int scanBlocks = (N + 255) / 256;
    uint2* Ah0     = (uint2*)alloc((size_t)N * DIM * 2);  // fp16 gather operand (ping)
    uint2* Ah1     = (uint2*)alloc((size_t)N * DIM * 2);  // fp16 pong
    uint2* Bh      = (uint2*)alloc((size_t)N * DIM * 2);  // agg output (fp16)
    _Float16* X3   = (_Float16*)alloc((size_t)N * DIM * 2);  // layer-3 fp16 output
    _Float16* Wt1  = (_Float16*)alloc((size_t)DIM * DIM * 2);
    _Float16* Wt2  = (_Float16*)alloc((size_t)DIM * DIM * 2);
    _Float16* Wt3  = (_Float16*)alloc((size_t)DIM * DIM * 2);
    float* ns      = (float*)alloc((size_t)N * 4);
    float* nd      = (float*)alloc((size_t)N * 4);
    int*   inc     = (int*)alloc((size_t)N * 4);
    unsigned* partial = (unsigned*)alloc((size_t)2 * HIST_R * HIST_S * LDSW * 4);  // 12.8 MB
    int*   cur     = (int*)alloc((size_t)HIST_R * HIST_S * NPR * 4);               // 12.8 MB
    int*   row_ptr = (int*)alloc((size_t)(N + 1) * 4);
    int*   csr     = (int*)alloc((size_t)E * 4);
    float* gsum    = (float*)alloc((size_t)G * DIM * 4);
    int*   gcnt    = (int*)alloc((size_t)G * 4);
    int*   bsum    = (int*)alloc((size_t)scanBlocks * 4);

    hipMemsetAsync(gsum, 0, (size_t)G * DIM * 4, stream);
    hipMemsetAsync(gcnt, 0, (size_t)G * 4, stream);

    // degrees via LDS histograms (no global atomics)
    k_hist<<<2 * HIST_R * HIST_S, 256, 0, stream>>>(src, dst, partial, E);
    int mergeThreads = 2 * HIST_R * LDSW;
    k_hist_merge<<<(mergeThreads + 255) / 256, 256, 0, stream>>>(partial, ns, nd, inc, N);

    k_scan_partial<<<scanBlocks, 256, 0, stream>>>(inc, bsum, N);
    k_scan_top<<<1, 256, 0, stream>>>(bsum, scanBlocks);
    k_scan_write<<<scanBlocks, 256, 0, stream>>>(inc, bsum, row_ptr, N);

    // per-(range,slice) cursors from histogram prefix; CSR fill with LDS cursors
    int curThreads = HIST_R * LDSW;
    k_cursor<<<(curThreads + 255) / 256, 256, 0, stream>>>(partial, row_ptr, cur, N);
    k_fill2<<<HIST_R * HIST_S, 256, 0, stream>>>(src, dst, cur, csr, E);

    // weights -> fp16 transposed (single launch)
    k_w2half3<<<192, 256, 0, stream>>>(W1, W2, W3, Wt1, Wt2, Wt3);

    int aggBlocks  = (N * 64 + 255) / 256;
    int gemmBlocks = (N + 63) / 64;

    // layer 1: Ah0 = fp16(h * ns); agg -> Bh (fp16); mfma gemm -> Ah1 (fp16, *ns)
    k_h2half<<<(N * 32 + 255) / 256, 256, 0, stream>>>((const float4*)h, ns, Ah0, N);
    k_agg<<<aggBlocks, 256, 0, stream>>>(Ah0, row_ptr, csr, nd, Bh, N);
    k_gemm_mfma<true><<<gemmBlocks, 256, 0, stream>>>((const _Float16*)Bh, Wt1, b1, ns, (_Float16*)Ah1, N);
    // layer 2
    k_agg<<<aggBlocks, 256, 0, stream>>>(Ah1, row_ptr, csr, nd, Bh, N);
    k_gemm_mfma<true><<<gemmBlocks, 256, 0, stream>>>((const _Float16*)Bh, Wt2, b2, ns, (_Float16*)Ah0, N);
    // layer 3 (fp16 out, no ns)
    k_agg<<<aggBlocks, 256, 0, stream>>>(Ah0, row_ptr, csr, nd, Bh, N);
    k_gemm_mfma<false><<<gemmBlocks, 256, 0, stream>>>((const _Float16*)Bh, Wt3, b3, ns, X3, N);

    k_pool_partial<<<(N + POOL_NODES - 1) / POOL_NODES, 128, 0, stream>>>(X3, gid, gsum, gcnt, N);
    k_finalize<<<(G * DIM + 255) / 256, 256, 0, stream>>>(gsum, gcnt, out, G);
}